// Round 19
// baseline (1013.416 us; speedup 1.0000x reference)
//
#include <hip/hip_runtime.h>
#include <math.h>

#define N_ 64
#define T_ 256
#define I_ 512
#define H_ 1024

typedef unsigned short u16;
typedef unsigned int u32;
typedef unsigned long long u64;
typedef short bf16x8 __attribute__((ext_vector_type(8)));
typedef float f32x4 __attribute__((ext_vector_type(4)));
typedef u16 u16x4 __attribute__((ext_vector_type(4)));

__device__ __forceinline__ u16 f2bf(float f) {
    union { float f; unsigned int u; } x; x.f = f;
    unsigned int r = (x.u + 0x7FFFu + ((x.u >> 16) & 1u)) >> 16;
    return (u16)r;
}
__device__ __forceinline__ float bf2f(u16 u) {
    union { unsigned int u; float f; } x; x.u = ((unsigned int)u) << 16;
    return x.f;
}
__device__ __forceinline__ float sigf(float v) {
    return 1.0f / (1.0f + __expf(-v));
}
__device__ __forceinline__ float tanhfast(float x) {
    float e = __expf(2.0f * x);
    return 1.0f - 2.0f / (e + 1.0f);   // NaN-free at +-inf
}

// cached global->LDS (weight staging)
__device__ __forceinline__ void gload_lds16n(const void* g, void* l) {
    __builtin_amdgcn_global_load_lds(
        (__attribute__((address_space(1))) void*)(g),
        (__attribute__((address_space(3))) void*)(l), 16, 0, 0);
}

#define VMW(Ncnt) do { \
    asm volatile("s_waitcnt vmcnt(" #Ncnt ")" ::: "memory"); \
    __builtin_amdgcn_sched_barrier(0); } while (0)

// c storage split: n<32 -> cA (upper half of out2), n>=32 -> cB (ws)
__device__ __forceinline__ float* c_ptr(int n, int t, int j, float* cA, float* cB) {
    return (n < 32) ? (cA + (((size_t)(n * 256 + t)) << 10) + j)
                    : (cB + (((size_t)((n - 32) * 256 + t)) << 10) + j);
}

// ---------------- prep kernels ----------------

// Packed row rp = jp*4+g ; PERMUTED source: within each 16-block of packed unit
// index jp (loc = a*4+b), the true unit is loc' = b*4+a (involution). This makes
// a lane's 4 quarter-cells land on CONTIGUOUS true units -> coalesced stores.
__global__ __launch_bounds__(256) void pack_weights(
    const float* __restrict__ W_ih, const float* __restrict__ W_hh,
    const float* __restrict__ b_ih, const float* __restrict__ b_hh,
    u16* __restrict__ Wp, float* __restrict__ bp)
{
    const int rp = blockIdx.x;            // 0..4095
    const int g = rp & 3, jp = rp >> 2;
    const int loc = jp & 15;
    const int jsrc = (jp & ~15) + ((loc & 3) << 2) + (loc >> 2);
    const int src = g * H_ + jsrc;
    const float* wi = W_ih + (size_t)src * I_;
    const float* wh = W_hh + (size_t)src * H_;
    u16* dst = Wp + (size_t)rp * (I_ + H_);
    for (int k = threadIdx.x; k < I_; k += 256) dst[k] = f2bf(wi[k]);
    for (int k = threadIdx.x; k < H_; k += 256) dst[I_ + k] = f2bf(wh[k]);
    if (threadIdx.x == 0) bp[rp] = b_ih[src] + b_hh[src];
}

__global__ __launch_bounds__(256) void conv_x(
    const float* __restrict__ x, u16* __restrict__ x_tb)
{
    const int t = blockIdx.x, n = blockIdx.y;
    const float* s = x + ((size_t)n * T_ + t) * I_;
    u16* d = x_tb + ((size_t)t * N_ + n) * I_;
    for (int k = threadIdx.x; k < I_; k += 256) d[k] = f2bf(s[k]);
}

__global__ __launch_bounds__(256) void conv_wout(
    const float* __restrict__ W, u16* __restrict__ Wb)
{
    const size_t base = (size_t)blockIdx.x * 1024 + threadIdx.x;
    #pragma unroll
    for (int q = 0; q < 4; ++q) Wb[base + q * 256] = f2bf(W[base + q * 256]);
}

// hxbf[n][j] = bf16(hx[n,0,j])   (UNscaled; only read by rows with r=1)
__global__ __launch_bounds__(256) void conv_hx(
    const float* __restrict__ hx, u16* __restrict__ hxbf)
{
    const int idx = blockIdx.x * 256 + threadIdx.x;   // 65536
    const int n = idx >> 10, j = idx & (H_ - 1);
    hxbf[idx] = f2bf(hx[(size_t)n * T_ * H_ + j]);
}

// rel[n,t] = 0 if is_init, else distance to previous reset (t+1 if none).
__global__ __launch_bounds__(256) void prep_rel(
    const int* __restrict__ is_init, u16* __restrict__ rel16)
{
    __shared__ u16 ii[256];
    const int n = blockIdx.x, t = threadIdx.x;
    ii[t] = (u16)(is_init[n * T_ + t] != 0);
    __syncthreads();
    int rel = t + 1;
    for (int d = 0; d <= t; ++d) {
        if (ii[t - d]) { rel = d; break; }
    }
    rel16[n * T_ + t] = (u16)rel;
}

// Per batch-group: LDS histogram of rel -> exclusive offsets -> scatter CSR.
__global__ __launch_bounds__(256) void prep_bucket(
    const u16* __restrict__ rel16, u16* __restrict__ entries, u32* __restrict__ offs)
{
    __shared__ u32 hist[258];
    __shared__ u32 offsh[258];
    const int g = blockIdx.x, tid = threadIdx.x;
    for (int i = tid; i < 258; i += 256) hist[i] = 0;
    __syncthreads();
    for (int i = tid; i < 4096; i += 256) {
        const int n = g * 16 + (i & 15), t = i >> 4;
        atomicAdd(&hist[rel16[n * T_ + t]], 1u);
    }
    __syncthreads();
    if (tid == 0) {
        u32 acc = 0;
        for (int s = 0; s < 258; ++s) { offsh[s] = acc; acc += hist[s]; }
    }
    __syncthreads();
    for (int i = tid; i < 258; i += 256) {
        offs[g * 258 + i] = offsh[i];
        hist[i] = offsh[i];          // reuse as scatter cursor
    }
    __syncthreads();
    for (int i = tid; i < 4096; i += 256) {
        const int n = g * 16 + (i & 15), t = i >> 4;
        const int rel = rel16[n * T_ + t];
        const u32 slot = atomicAdd(&hist[rel], 1u);
        entries[g * 4096 + slot] = (u16)((t << 6) | n);
    }
}

// ---------------- x-gate precompute: 256x256-tile GEMM [proven r11] ----------
__global__ __launch_bounds__(512) __attribute__((amdgpu_waves_per_eu(2, 2)))
void xgates_mfma(
    const u16* __restrict__ x_tb,   // [16384][512]
    const u16* __restrict__ Wp,     // [4096][1536] (x-part = first 512)
    const float* __restrict__ bp,   // [4096]
    u16* __restrict__ Xg)           // [16384][4096]
{
    __shared__ u16 bls[2][8192];    // 2 x 16KB, lane-major per 16-col tile
    const int bx = blockIdx.x, by = blockIdx.y;
    const int tid = threadIdx.x;
    const int v = tid >> 6, l = tid & 63;
    const int l15 = l & 15, lh = l >> 4;
    const int rowb = bx * 256 + v * 32;
    const int colb = by * 256;

    const u16* ap0 = x_tb + (size_t)(rowb + l15) * I_ + lh * 8;
    const u16* ap1 = x_tb + (size_t)(rowb + 16 + l15) * I_ + lh * 8;
    const u16* bs0 = Wp + (size_t)(colb + (2 * v) * 16 + l15) * 1536 + lh * 8;
    const u16* bs1 = Wp + (size_t)(colb + (2 * v + 1) * 16 + l15) * 1536 + lh * 8;

    f32x4 acc[2][16];
    #pragma unroll
    for (int m = 0; m < 2; ++m)
        #pragma unroll
        for (int nt = 0; nt < 16; ++nt) acc[m][nt] = f32x4{0.f, 0.f, 0.f, 0.f};

#define STAGEX(S, B) do { \
    gload_lds16n(bs0 + (S) * 32, (char*)bls[B] + (2 * v) * 1024); \
    gload_lds16n(bs1 + (S) * 32, (char*)bls[B] + (2 * v + 1) * 1024); } while (0)

    STAGEX(0, 0);
    VMW(0); __syncthreads();
    int buf = 0;
    for (int s = 0; s < 16; ++s) {
        if (s < 15) STAGEX(s + 1, buf ^ 1);
        bf16x8 a0 = *(const bf16x8*)(ap0 + s * 32);
        bf16x8 a1 = *(const bf16x8*)(ap1 + s * 32);
        const char* bb = (const char*)bls[buf];
        #pragma unroll
        for (int nt = 0; nt < 16; ++nt) {
            bf16x8 bfr = *(const bf16x8*)(bb + nt * 1024 + l * 16);
            acc[0][nt] = __builtin_amdgcn_mfma_f32_16x16x32_bf16(a0, bfr, acc[0][nt], 0, 0, 0);
            acc[1][nt] = __builtin_amdgcn_mfma_f32_16x16x32_bf16(a1, bfr, acc[1][nt], 0, 0, 0);
        }
        VMW(0); __syncthreads();
        buf ^= 1;
    }
#undef STAGEX

    #pragma unroll
    for (int nt = 0; nt < 16; ++nt) {
        const int col = colb + nt * 16 + l15;
        const float bo = bp[col];
        #pragma unroll
        for (int mt = 0; mt < 2; ++mt)
            #pragma unroll
            for (int rg = 0; rg < 4; ++rg) {
                const int row = rowb + mt * 16 + lh * 4 + rg;
                Xg[(size_t)row * 4096 + col] = f2bf(acc[mt][nt][rg] + bo);
            }
    }
}

// ---------------- segment-parallel LSTM [r18-proven] -------------------------
__global__ __launch_bounds__(256, 1) void lstm_seg(
    const u16* __restrict__ Xg,      // [16384][4096] bf16, PACKED unit order
    const u16* __restrict__ Wp,      // [4096][1536]
    const float* __restrict__ cx,    // (N,T,H) fp32
    const u16* __restrict__ hxbf,    // [64][1024] bf16
    const u16* __restrict__ entries, // [4][4096] CSR by rel
    const u32* __restrict__ offs,    // [4][258]
    u16* __restrict__ hs,            // [64][256][1024] bf16 (out2 lower)
    float* __restrict__ cA,          // [32][256][1024] f32 (out2 upper, n<32)
    float* __restrict__ cB,          // [32][256][1024] f32 (ws, n>=32)
    float* __restrict__ c_final,     // [64][1024] f32
    u32* __restrict__ flags)         // [4][64] x16-spaced
{
    __shared__ u16 wls[65536];       // 128 KB: h-part weights, quarter-major
    const int tid = threadIdx.x;
    const int v = tid >> 6, l = tid & 63;
    const int l15 = l & 15, lh = l >> 4;
    const int u = blockIdx.x & 63, g = blockIdx.x >> 6;

    // preload weights [r13-proven]: wave v stages quarter v (rows u*64+v*16..+15)
    {
        const u16* src = Wp + (size_t)(u * 64 + v * 16 + l15) * 1536 + I_ + lh * 8;
        char* dst = (char*)wls + v * 32768;
        #pragma unroll
        for (int kk = 0; kk < 32; ++kk)
            gload_lds16n(src + kk * 32, dst + kk * 1024);
    }

    const u16* gent = entries + g * 4096;
    const u32* goff = offs + g * 258;
    u32* gflags = flags + g * 64 * 16;
    const char* wlsb = (const char*)wls;

    VMW(0);
    __syncthreads();

    // ---- s = 0: elementwise rows; thread owns TRUE units (jt, jt+1) ----
    {
        const int m0 = (int)goff[1];
        const int gtid = u * 256 + tid;       // 0..16383 within group
        for (int cell = gtid; cell < m0 * 512; cell += 64 * 256) {
            const int ri = cell >> 9, jj = cell & 511;
            const int jt = jj * 2;
            const u16 e = gent[ri];
            const int t = e >> 6, n = e & 63;
            const int loc = jt & 15;
            const int jp = (jt & ~15) + ((loc & 3) << 2) + (loc >> 2);
            const u16* xrow = Xg + ((size_t)t * 64 + n) * 4096;
            const u16x4 xa = *(const u16x4*)(xrow + 4 * jp);
            const u16x4 xb = *(const u16x4*)(xrow + 4 * jp + 16);
            const float c0 = sigf(bf2f(xa[0])) * tanhfast(bf2f(xa[2]));
            const float h0 = sigf(bf2f(xa[3])) * tanhfast(c0);
            const float c1 = sigf(bf2f(xb[0])) * tanhfast(bf2f(xb[2]));
            const float h1 = sigf(bf2f(xb[3])) * tanhfast(c1);
            const size_t hrow = ((size_t)n * 256 + t) * 1024;
            __hip_atomic_store((u32*)(hs + hrow + jt),
                               (u32)f2bf(h0) | ((u32)f2bf(h1) << 16),
                               __ATOMIC_RELAXED, __HIP_MEMORY_SCOPE_AGENT);
            const u64 cpk = (u64)__float_as_uint(c0) | ((u64)__float_as_uint(c1) << 32);
            __hip_atomic_store((u64*)c_ptr(n, t, jt, cA, cB), cpk,
                               __ATOMIC_RELAXED, __HIP_MEMORY_SCOPE_AGENT);
            if (t == T_ - 1) *(float2*)(c_final + n * H_ + jt) = float2{c0, c1};
        }
    }
    VMW(0);
    __syncthreads();
    if (tid == 0)
        __hip_atomic_store(gflags + u * 16, 1u,
                           __ATOMIC_RELAXED, __HIP_MEMORY_SCOPE_AGENT);
    if (tid < 64) {
        while (__hip_atomic_load(gflags + tid * 16, __ATOMIC_RELAXED,
                                 __HIP_MEMORY_SCOPE_AGENT) < 1u)
            __builtin_amdgcn_s_sleep(1);
    }
    __syncthreads();
    __builtin_amdgcn_sched_barrier(0);

    // double-buffer state
    bf16x8 Aa[32], Ba[32];
    u16x4 Axg[4], Bxg[4];
    float Acp[4], Bcp[4];
    int At = 0, An = 0, Bt = 0, Bn = 0;
    bool Av = false, Bv = false;

#define LOADT(P, MT) do { \
    const int ridx_ = base + (MT) * 16 + l15; \
    P##v = (ridx_ <= last); \
    const u16 e_ = gent[P##v ? ridx_ : last]; \
    P##t = e_ >> 6; P##n = e_ & 63; \
    const u16* rowsrc_ = (P##t == 0) ? (hxbf + P##n * 1024) \
                       : (hs + ((size_t)P##n * 256 + (P##t - 1)) * 1024); \
    const char* lsrc_ = (const char*)rowsrc_ + lh * 16; \
    _Pragma("unroll") \
    for (int kk_ = 0; kk_ < 32; ++kk_) \
        P##a[kk_] = *(const bf16x8*)(lsrc_ + kk_ * 64); \
    const u16* xrow_ = Xg + ((size_t)P##t * 64 + P##n) * 4096; \
    _Pragma("unroll") \
    for (int q_ = 0; q_ < 4; ++q_) { \
        P##xg[q_] = *(const u16x4*)(xrow_ + 4 * (u * 16 + q_ * 4 + lh)); \
        const int jt_ = u * 16 + lh * 4 + q_; \
        P##cp[q_] = (P##t == 0) ? cx[(size_t)P##n * T_ * H_ + jt_] \
                                : *c_ptr(P##n, P##t - 1, jt_, cA, cB); \
    } \
} while (0)

#define PROCT(P) do { \
    f32x4 acc_[4]; \
    _Pragma("unroll") \
    for (int q_ = 0; q_ < 4; ++q_) acc_[q_] = f32x4{0.f, 0.f, 0.f, 0.f}; \
    _Pragma("unroll") \
    for (int q_ = 0; q_ < 4; ++q_) { \
        _Pragma("unroll") \
        for (int kk_ = 0; kk_ < 32; ++kk_) { \
            bf16x8 wf_ = *(const bf16x8*)(wlsb + q_ * 32768 + kk_ * 1024 + l * 16); \
            acc_[q_] = __builtin_amdgcn_mfma_f32_16x16x32_bf16(wf_, P##a[kk_], acc_[q_], 0, 0, 0); \
        } \
    } \
    float cn_[4], hv_[4]; \
    _Pragma("unroll") \
    for (int q_ = 0; q_ < 4; ++q_) { \
        const float ig_ = acc_[q_][0] + bf2f(P##xg[q_][0]); \
        const float fg_ = acc_[q_][1] + bf2f(P##xg[q_][1]); \
        const float gg_ = acc_[q_][2] + bf2f(P##xg[q_][2]); \
        const float og_ = acc_[q_][3] + bf2f(P##xg[q_][3]); \
        cn_[q_] = sigf(fg_) * P##cp[q_] + sigf(ig_) * tanhfast(gg_); \
        hv_[q_] = sigf(og_) * tanhfast(cn_[q_]); \
    } \
    if (P##v) { \
        const int jt0_ = u * 16 + lh * 4; \
        const u64 hp_ = (u64)f2bf(hv_[0]) | ((u64)f2bf(hv_[1]) << 16) \
                      | ((u64)f2bf(hv_[2]) << 32) | ((u64)f2bf(hv_[3]) << 48); \
        __hip_atomic_store((u64*)(hs + ((size_t)P##n * 256 + P##t) * 1024 + jt0_), \
                           hp_, __ATOMIC_RELAXED, __HIP_MEMORY_SCOPE_AGENT); \
        float* cp0_ = c_ptr(P##n, P##t, jt0_, cA, cB); \
        const u64 c01_ = (u64)__float_as_uint(cn_[0]) | ((u64)__float_as_uint(cn_[1]) << 32); \
        const u64 c23_ = (u64)__float_as_uint(cn_[2]) | ((u64)__float_as_uint(cn_[3]) << 32); \
        __hip_atomic_store((u64*)cp0_, c01_, __ATOMIC_RELAXED, __HIP_MEMORY_SCOPE_AGENT); \
        __hip_atomic_store((u64*)(cp0_ + 2), c23_, __ATOMIC_RELAXED, __HIP_MEMORY_SCOPE_AGENT); \
        if (P##t == T_ - 1) \
            *(float4*)(c_final + P##n * H_ + jt0_) = float4{cn_[0], cn_[1], cn_[2], cn_[3]}; \
    } \
} while (0)

    // ---- iterations s = 1.. (exact bound: rows with rel >= s exist)
    for (int s = 1; s <= 256; ++s) {
        if (goff[s] >= 4096u) break;
        const int base = (int)goff[s];
        const int last = (int)goff[s + 1] - 1;
        const int ntiles = ((last + 1 - base) + 15) >> 4;

        int mt = v;
        if (mt < ntiles) {
            LOADT(A, mt);
            while (true) {
                int nx = mt + 4;
                if (nx < ntiles) LOADT(B, nx);
                PROCT(A);
                mt = nx;
                if (mt >= ntiles) break;
                nx = mt + 4;
                if (nx < ntiles) LOADT(A, nx);
                PROCT(B);
                mt = nx;
                if (mt >= ntiles) break;
            }
        }

        // group barrier: phase s complete
        VMW(0);
        __syncthreads();
        if (tid == 0)
            __hip_atomic_store(gflags + u * 16, (u32)(s + 1),
                               __ATOMIC_RELAXED, __HIP_MEMORY_SCOPE_AGENT);
        if (tid < 64) {
            while (__hip_atomic_load(gflags + tid * 16, __ATOMIC_RELAXED,
                                     __HIP_MEMORY_SCOPE_AGENT) < (u32)(s + 1))
                __builtin_amdgcn_s_sleep(1);
        }
        __syncthreads();
        __builtin_amdgcn_sched_barrier(0);
    }
#undef LOADT
#undef PROCT
}

// ---------------- output projection: 256x256-tile GEMM + mish ----------------
// r18 counters: WRITE_SIZE 2.25GB vs 67MB logical (~32x amplification on the
// scattered per-lane 4B stores), 71% HBM peak, dur 416us. Fix: LDS-staged
// epilogue — stage per-wave [4 rows][256 cols] f32 tiles in bls (dead after
// the K-loop), read back one float4/lane -> each wave store = 1KB contiguous
// (full 128B lines).
__global__ __launch_bounds__(512) __attribute__((amdgpu_waves_per_eu(2, 2)))
void out_proj_mfma(
    const u16* __restrict__ hs,     // [16384][1024]
    const u16* __restrict__ Wo,     // [1024][1024]
    const float* __restrict__ b_out,
    float* __restrict__ out0)       // [16384][1024]
{
    __shared__ u16 bls[2][8192];    // 2 x 16KB (K-loop B-tiles; then f32 staging)
    const int bx = blockIdx.x, by = blockIdx.y;
    const int tid = threadIdx.x;
    const int v = tid >> 6, l = tid & 63;
    const int l15 = l & 15, lh = l >> 4;
    const int rowb = bx * 256 + v * 32;
    const int colb = by * 256;

    const u16* ap0 = hs + (size_t)(rowb + l15) * H_ + lh * 8;
    const u16* ap1 = hs + (size_t)(rowb + 16 + l15) * H_ + lh * 8;
    const u16* bs0 = Wo + (size_t)(colb + (2 * v) * 16 + l15) * H_ + lh * 8;
    const u16* bs1 = Wo + (size_t)(colb + (2 * v + 1) * 16 + l15) * H_ + lh * 8;

    f32x4 acc[2][16];
    #pragma unroll
    for (int m = 0; m < 2; ++m)
        #pragma unroll
        for (int nt = 0; nt < 16; ++nt) acc[m][nt] = f32x4{0.f, 0.f, 0.f, 0.f};

#define STAGEO(S, B) do { \
    gload_lds16n(bs0 + (S) * 32, (char*)bls[B] + (2 * v) * 1024); \
    gload_lds16n(bs1 + (S) * 32, (char*)bls[B] + (2 * v + 1) * 1024); } while (0)

    STAGEO(0, 0);
    VMW(0); __syncthreads();
    int buf = 0;
    for (int s = 0; s < 32; ++s) {
        if (s < 31) STAGEO(s + 1, buf ^ 1);
        bf16x8 a0 = *(const bf16x8*)(ap0 + s * 32);
        bf16x8 a1 = *(const bf16x8*)(ap1 + s * 32);
        const char* bb = (const char*)bls[buf];
        #pragma unroll
        for (int nt = 0; nt < 16; ++nt) {
            bf16x8 bfr = *(const bf16x8*)(bb + nt * 1024 + l * 16);
            acc[0][nt] = __builtin_amdgcn_mfma_f32_16x16x32_bf16(a0, bfr, acc[0][nt], 0, 0, 0);
            acc[1][nt] = __builtin_amdgcn_mfma_f32_16x16x32_bf16(a1, bfr, acc[1][nt], 0, 0, 0);
        }
        VMW(0); __syncthreads();
        buf ^= 1;
    }
#undef STAGEO

    // ---- LDS-staged epilogue: full-line coalesced stores ----
    // (K-loop ended with __syncthreads -> bls is dead; 8 waves x 4KB = 32KB)
    float* stg = (float*)((char*)bls + v * 4096);   // [4 rows][256 cols] f32
    #pragma unroll
    for (int mt = 0; mt < 2; ++mt) {
        #pragma unroll
        for (int rg = 0; rg < 4; ++rg) {
            #pragma unroll
            for (int nt = 0; nt < 16; ++nt) {
                const int col = colb + nt * 16 + l15;
                const float y = acc[mt][nt][rg] + b_out[col];
                const float sp = (y > 15.f) ? y : log1pf(__expf(y));
                stg[lh * 256 + nt * 16 + l15] = y * tanhfast(sp);
            }
            asm volatile("s_waitcnt lgkmcnt(0)" ::: "memory");
            __builtin_amdgcn_sched_barrier(0);
            #pragma unroll
            for (int r2 = 0; r2 < 4; ++r2) {
                const float4 vv = *(const float4*)((const char*)stg + r2 * 1024 + l * 16);
                const int row = rowb + mt * 16 + r2 * 4 + rg;
                *(float4*)(out0 + (size_t)row * H_ + colb + l * 4) = vv;
            }
            asm volatile("s_waitcnt lgkmcnt(0)" ::: "memory");  // WAR fence for next rg
            __builtin_amdgcn_sched_barrier(0);
        }
    }
}

// out1 = broadcast hs[:,255,:]  (hs in out2 region — MUST run before bcast_c)
__global__ __launch_bounds__(256) void bcast_h(
    const u16* __restrict__ hs, float* __restrict__ out1)
{
    const size_t total = (size_t)N_ * T_ * H_;
    for (size_t idx = (size_t)blockIdx.x * 256 + threadIdx.x; idx < total;
         idx += (size_t)gridDim.x * 256) {
        const int n = (int)(idx >> 18);
        const int j = (int)(idx & (H_ - 1));
        out1[idx] = bf2f(hs[((size_t)n * T_ + (T_ - 1)) * H_ + j]);
    }
}

__global__ __launch_bounds__(256) void bcast_c(
    const float* __restrict__ c_final, float* __restrict__ out2)
{
    const size_t total = (size_t)N_ * T_ * H_;
    for (size_t idx = (size_t)blockIdx.x * 256 + threadIdx.x; idx < total;
         idx += (size_t)gridDim.x * 256) {
        const int n = (int)(idx >> 18);
        const int j = (int)(idx & (H_ - 1));
        out2[idx] = c_final[n * H_ + j];
    }
}

extern "C" void kernel_launch(void* const* d_in, const int* in_sizes, int n_in,
                              void* d_out, int out_size, void* d_ws, size_t ws_size,
                              hipStream_t stream) {
    const float* x      = (const float*)d_in[0];
    const int*   is_ini = (const int*)  d_in[1];
    const float* hx     = (const float*)d_in[2];
    const float* cx     = (const float*)d_in[3];
    const float* W_ih   = (const float*)d_in[4];
    const float* W_hh   = (const float*)d_in[5];
    const float* b_ih   = (const float*)d_in[6];
    const float* b_hh   = (const float*)d_in[7];
    const float* W_out  = (const float*)d_in[8];
    const float* b_out  = (const float*)d_in[9];

    float* out0 = (float*)d_out;
    float* out1 = out0 + (size_t)N_ * T_ * H_;
    float* out2 = out1 + (size_t)N_ * T_ * H_;

    char* ws = (char*)d_ws;
    u16*   x_tb    = (u16*)  (ws + 0);          // 16,777,216
    u16*   Wp      = (u16*)  (ws + 16777216);   // 12,582,912
    float* bp      = (float*)(ws + 29360128);   // 16,384
    u16*   Wo_b    = (u16*)  (ws + 29376512);   // 2,097,152
    float* c_final = (float*)(ws + 31473664);   // 262,144
    u16*   hxbf    = (u16*)  (ws + 31735808);   // 131,072
    u16*   rel16   = (u16*)  (ws + 31866880);   // 32,768
    u16*   entries = (u16*)  (ws + 31899648);   // 32,768
    u32*   offs    = (u32*)  (ws + 31932416);   // 4,352 (pad)
    u32*   flags   = (u32*)  (ws + 31945472);   // 16,384   [4][64] x16-spaced
    float* cB      = (float*)(ws + 31961856);   // 33,554,432 (c for n>=32)
                                                // ws end ~65.5 MB (r2-proven size)

    u16*   Xg = (u16*)out0;             // 134.2 MB scratch (out0+out1), consumed
    u16*   hs = (u16*)out2;             // 33.55 MB (out2 lower half)
    float* cA = (float*)(out2 + (size_t)32 * 256 * 1024);  // out2 upper (n<32)

    hipMemsetAsync(flags, 0, 16384, stream);
    pack_weights<<<4096, 256, 0, stream>>>(W_ih, W_hh, b_ih, b_hh, Wp, bp);
    conv_x<<<dim3(T_, N_), 256, 0, stream>>>(x, x_tb);
    conv_wout<<<1024, 256, 0, stream>>>(W_out, Wo_b);
    conv_hx<<<256, 256, 0, stream>>>(hx, hxbf);
    prep_rel<<<64, 256, 0, stream>>>(is_ini, rel16);
    prep_bucket<<<4, 256, 0, stream>>>(rel16, entries, offs);

    xgates_mfma<<<dim3(64, 16), 512, 0, stream>>>(x_tb, Wp, bp, Xg);

    lstm_seg<<<256, 256, 0, stream>>>(Xg, Wp, cx, hxbf, entries, offs,
                                      hs, cA, cB, c_final, flags);

    out_proj_mfma<<<dim3(64, 4), 512, 0, stream>>>(hs, Wo_b, b_out, out0);
    bcast_h<<<2048, 256, 0, stream>>>(hs, out1);
    bcast_c<<<2048, 256, 0, stream>>>(c_final, out2);
}